// Round 6
// baseline (528.327 us; speedup 1.0000x reference)
//
#include <hip/hip_runtime.h>
#include <math.h>

#define ALPHA_SLOPE 0.2f

typedef _Float16 f16;
typedef f16 f16x4 __attribute__((ext_vector_type(4)));
typedef f16 f16x8 __attribute__((ext_vector_type(8)));
typedef float f32x4 __attribute__((ext_vector_type(4)));

constexpr int B_ = 8, N = 2048, F = 256, D = 128, H = 2;
constexpr int C2 = H * D;           // 256
constexpr int M_ = B_ * N;          // 16384
constexpr int NCH = 16;             // scan chunks
constexpr int CHL = N / NCH;        // 128

__device__ __forceinline__ float lrelu(float x) { return fmaxf(x, ALPHA_SLOPE * x); }

// ---------- x fp32 -> f16 (replicated for measurement) ----------
__global__ __launch_bounds__(256) void cvt_x_kernel(const float* __restrict__ x, f16* __restrict__ xh,
                                                    const int reps)
{
    for (int rep = 0; rep < reps; ++rep) {
        asm volatile("" ::: "memory");
        const int idx = (blockIdx.x * 256 + threadIdx.x) * 4;
        const float4 v = *(const float4*)&x[idx];
        f16x4 o; o[0] = (f16)v.x; o[1] = (f16)v.y; o[2] = (f16)v.z; o[3] = (f16)v.w;
        *(f16x4*)&xh[idx] = o;
    }
}

// ---------- both layers' W -> WcT[layer][c][k] f16 ----------
__global__ __launch_bounds__(256) void cvt_w_kernel(
    const float* __restrict__ W00, const float* __restrict__ W01,
    const float* __restrict__ W10, const float* __restrict__ W11,
    f16* __restrict__ WcT)
{
    const int c = blockIdx.x, k = threadIdx.x, layer = blockIdx.y;
    const float* __restrict__ W0 = layer ? W10 : W00;
    const float* __restrict__ W1 = layer ? W11 : W01;
    const float v = (c < D) ? W0[k * D + c] : W1[k * D + (c - D)];
    WcT[(size_t)layer * C2 * C2 + c * C2 + k] = (f16)v;
}

// ---------- fused: h = xh@WcT^T + bias (MFMA), coalesced h store, l/r from LDS tile ----------
__global__ __launch_bounds__(256) void gemm_lr_kernel(
    const f16* __restrict__ xh, const f16* __restrict__ WcT,
    const float* __restrict__ b0, const float* __restrict__ b1,
    const float* __restrict__ a0, const float* __restrict__ a1,
    float* __restrict__ h,
    float* __restrict__ l0, float* __restrict__ r0,
    float* __restrict__ l1, float* __restrict__ r1,
    const int reps)
{
    __shared__ float hts[64][C2 + 4];
    f16 (*xs)[C2 + 8] = (f16 (*)[C2 + 8])hts;

    const int t = threadIdx.x;
    const int row0 = blockIdx.x * 64;
    for (int rep = 0; rep < reps; ++rep) {
        asm volatile("" ::: "memory");
#pragma unroll
        for (int p = 0; p < 8; ++p) {
            const int q = p * 256 + t;
            const int row = q >> 5, cc = q & 31;
            *(f16x8*)&xs[row][cc * 8] = *(const f16x8*)&xh[(size_t)(row0 + row) * C2 + cc * 8];
        }
        __syncthreads();
        const int w = t >> 6, l = t & 63;
        const int fm = l & 15, fk = (l >> 4) * 8;
        f32x4 acc[4][4] = {};
#pragma unroll
        for (int ks = 0; ks < 8; ++ks) {
            f16x8 af[4], bf[4];
#pragma unroll
            for (int rt = 0; rt < 4; ++rt)
                af[rt] = *(const f16x8*)&xs[rt * 16 + fm][ks * 32 + fk];
#pragma unroll
            for (int ct = 0; ct < 4; ++ct) {
                const int col = w * 64 + ct * 16 + fm;
                bf[ct] = *(const f16x8*)&WcT[(size_t)col * C2 + ks * 32 + fk];
            }
#pragma unroll
            for (int rt = 0; rt < 4; ++rt)
#pragma unroll
                for (int ct = 0; ct < 4; ++ct)
                    acc[rt][ct] = __builtin_amdgcn_mfma_f32_16x16x32_f16(af[rt], bf[ct], acc[rt][ct], 0, 0, 0);
        }
        __syncthreads();
#pragma unroll
        for (int rt = 0; rt < 4; ++rt)
#pragma unroll
            for (int ct = 0; ct < 4; ++ct) {
                const int col = w * 64 + ct * 16 + fm;
                const float bias = (col < D) ? b0[col] : b1[col - D];
#pragma unroll
                for (int q = 0; q < 4; ++q) {
                    const int row = rt * 16 + (l >> 4) * 4 + q;
                    hts[row][col] = acc[rt][ct][q] + bias;
                }
            }
        __syncthreads();
#pragma unroll
        for (int p = 0; p < 16; ++p) {
            const int q = p * 256 + t;
            const int row = q >> 6, c4 = q & 63;
            *(float4*)&h[(size_t)(row0 + row) * C2 + c4 * 4] = *(const float4*)&hts[row][c4 * 4];
        }
        const int lrow = w * 16 + (l & 15);
        const int qtr = l >> 4;
        const float* __restrict__ ab = (qtr >= 2) ? a1 : a0;
        const int cb = (qtr & 1) * 64;
        float lv = 0.f, rv = 0.f;
#pragma unroll
        for (int c4 = 0; c4 < 16; ++c4) {
            const float4 hv = *(const float4*)&hts[lrow][qtr * 64 + c4 * 4];
            const float4 alv = *(const float4*)&ab[cb + c4 * 4];
            const float4 arv = *(const float4*)&ab[128 + cb + c4 * 4];
            lv += hv.x * alv.x + hv.y * alv.y + hv.z * alv.z + hv.w * alv.w;
            rv += hv.x * arv.x + hv.y * arv.y + hv.z * arv.z + hv.w * arv.w;
        }
        lv += __shfl_xor(lv, 16, 64);
        rv += __shfl_xor(rv, 16, 64);
        const int grow = row0 + lrow;
        if (qtr == 0) { l0[grow] = lv; r0[grow] = rv; }
        else if (qtr == 2) { l1[grow] = lv; r1[grow] = rv; }
        __syncthreads();   // protect LDS reuse across reps
    }
}

// ---------- rank sort + k_i count ----------
__global__ __launch_bounds__(256) void rank_kernel(
    const float* __restrict__ r0, const float* __restrict__ r1,
    const float* __restrict__ l0, const float* __restrict__ l1,
    float* __restrict__ rs_s, int* __restrict__ perm, int* __restrict__ kout,
    const int reps)
{
    const int bh = blockIdx.y;
    const float* __restrict__ r = ((bh & 1) ? r1 : r0) + (size_t)(bh >> 1) * N;
    const float* __restrict__ lp = ((bh & 1) ? l1 : l0) + (size_t)(bh >> 1) * N;
    __shared__ float rl[N];
    const int t = threadIdx.x;
    for (int j = t; j < N; j += 256) rl[j] = r[j];
    __syncthreads();
    for (int rep = 0; rep < reps; ++rep) {
        asm volatile("" ::: "memory");
        const int e = blockIdx.x * 256 + t;
        const float re = rl[e];
        const float thr = -lp[e];
        const int lo = blockIdx.x * 256, hi = lo + 256;
        int cnt = 0, k2 = 0;
        for (int j = 0; j < lo; j += 4) {
            const float4 v = *(const float4*)&rl[j];
            cnt += (v.x >= re) + (v.y >= re) + (v.z >= re) + (v.w >= re);
            k2  += (v.x >= thr) + (v.y >= thr) + (v.z >= thr) + (v.w >= thr);
        }
        for (int j = lo; j < hi; j += 4) {
            const float4 v = *(const float4*)&rl[j];
            cnt += (v.x > re) || (v.x == re && (j + 0) < e);
            cnt += (v.y > re) || (v.y == re && (j + 1) < e);
            cnt += (v.z > re) || (v.z == re && (j + 2) < e);
            cnt += (v.w > re) || (v.w == re && (j + 3) < e);
            k2  += (v.x >= thr) + (v.y >= thr) + (v.z >= thr) + (v.w >= thr);
        }
        for (int j = hi; j < N; j += 4) {
            const float4 v = *(const float4*)&rl[j];
            cnt += (v.x > re) + (v.y > re) + (v.z > re) + (v.w > re);
            k2  += (v.x >= thr) + (v.y >= thr) + (v.z >= thr) + (v.w >= thr);
        }
        const size_t g = (size_t)bh * N;
        rs_s[g + cnt] = re;
        perm[g + cnt] = e;
        kout[g + e] = k2;
    }
}

// ---------- fused chunk scans ----------
__global__ __launch_bounds__(256) void scanA_kernel(
    const float* __restrict__ h, const int* __restrict__ perm,
    const float* __restrict__ rs_s,
    f16* __restrict__ PA, f16* __restrict__ PB,
    float* __restrict__ SAloc, float* __restrict__ SBloc,
    float* __restrict__ totA, float* __restrict__ totB,
    float* __restrict__ stA, float* __restrict__ stB,
    const int reps)
{
    const int chunk = blockIdx.x, bh = blockIdx.y;
    const int b = bh >> 1, head = bh & 1;
    __shared__ float hs[CHL][D];
    __shared__ int pj[CHL];
    __shared__ float wA[CHL], wB[CHL];
    __shared__ float buf[256];
    const int t = threadIdx.x;
    const size_t g = (size_t)bh * N + chunk * CHL;
    for (int rep = 0; rep < reps; ++rep) {
        asm volatile("" ::: "memory");
        const float c1 = rs_s[(size_t)bh * N];
        if (t < CHL) {
            pj[t] = perm[g + t];
            const float rr = rs_s[g + t];
            const float eA = __expf(rr - c1);
            const float eB = __expf(0.2f * (rr - c1));
            wA[t] = eA; wB[t] = eB;
            buf[t] = eA;
        } else {
            const float rr = rs_s[g + (127 - (t - 128))];
            buf[t] = __expf(0.2f * (rr - c1));
        }
        __syncthreads();
        const int li = t & 127;
#pragma unroll
        for (int off = 1; off < 128; off <<= 1) {
            const float v = (li >= off) ? buf[t - off] : 0.f;
            __syncthreads();
            buf[t] += v;
            __syncthreads();
        }
        if (t < 128) SAloc[g + t] = buf[t];
        else SBloc[g + (127 - li)] = buf[t];
        if (t == 127) stA[bh * NCH + chunk] = buf[127];
        if (t == 255) stB[bh * NCH + chunk] = buf[255];
#pragma unroll
        for (int p = 0; p < 16; ++p) {
            const int q = p * 256 + t;
            const int row = q >> 5, c4 = q & 31;
            const float* src = h + (size_t)(b * N + pj[row]) * C2 + head * D;
            *(float4*)&hs[row][c4 * 4] = *(const float4*)&src[c4 * 4];
        }
        __syncthreads();
        if (t < D) {
            const int d = t;
            float acc = 0.f;
            for (int j = 0; j < CHL; ++j) {
                acc = fmaf(wA[j], hs[j][d], acc);
                PA[(g + j) * D + d] = (f16)acc;
            }
            totA[(size_t)(bh * NCH + chunk) * D + d] = acc;
        } else {
            const int d = t - D;
            float acc = 0.f;
            for (int jj = 0; jj < CHL; ++jj) {
                const int j = CHL - 1 - jj;
                acc = fmaf(wB[j], hs[j][d], acc);
                PB[(g + j) * D + d] = (f16)acc;
            }
            totB[(size_t)(bh * NCH + chunk) * D + d] = acc;
        }
        __syncthreads();   // protect LDS reuse across reps
    }
}

// ---------- chunk offsets ----------
__global__ __launch_bounds__(128) void scanB_kernel(
    const float* __restrict__ totA, const float* __restrict__ totB,
    const float* __restrict__ stA, const float* __restrict__ stB,
    float* __restrict__ AOff, float* __restrict__ BOffS,
    float* __restrict__ sAOff, float* __restrict__ sBOff,
    const int reps)
{
    const int bh = blockIdx.x, d = threadIdx.x;
    for (int rep = 0; rep < reps; ++rep) {
        asm volatile("" ::: "memory");
        float accA = 0.f;
        for (int q = 0; q < NCH; ++q) {
            AOff[(size_t)(bh * NCH + q) * D + d] = accA;
            accA += totA[(size_t)(bh * NCH + q) * D + d];
        }
        float accB = 0.f;
        for (int q = NCH - 1; q >= 0; --q) {
            BOffS[(size_t)(bh * NCH + q) * D + d] = accB;
            accB += totB[(size_t)(bh * NCH + q) * D + d];
        }
        if (d == 0) {
            float a = 0.f;
            for (int q = 0; q < NCH; ++q) { sAOff[bh * NCH + q] = a; a += stA[bh * NCH + q]; }
        } else if (d == 1) {
            float a = 0.f;
            for (int q = NCH - 1; q >= 0; --q) { sBOff[bh * NCH + q] = a; a += stB[bh * NCH + q]; }
        }
    }
}

// ---------- output ----------
__global__ __launch_bounds__(256) void out_kernel(
    const float* __restrict__ h,
    const float* __restrict__ l0v, const float* __restrict__ l1v,
    const float* __restrict__ r0v, const float* __restrict__ r1v,
    const int* __restrict__ perm, const float* __restrict__ rs_s,
    const int* __restrict__ kout,
    const float* __restrict__ SAloc, const float* __restrict__ SBloc,
    const float* __restrict__ sAOff, const float* __restrict__ sBOff,
    const f16* __restrict__ PA, const f16* __restrict__ PB,
    const float* __restrict__ AOff, const float* __restrict__ BOffS,
    float* __restrict__ out_f32, f16* __restrict__ out_f16, const int final_layer,
    const int reps)
{
    const int head = blockIdx.y, b = blockIdx.z;
    const int bh = b * H + head;
    const float* __restrict__ lv = (head ? l1v : l0v) + (size_t)b * N;
    const float* __restrict__ rv = (head ? r1v : r0v) + (size_t)b * N;
    const int t = threadIdx.x;
    const size_t gb = (size_t)bh * N;
    for (int rep = 0; rep < reps; ++rep) {
        asm volatile("" ::: "memory");
        const int i = blockIdx.x * 16 + (t >> 4);
        const int c0 = (t & 15) * 8;
        const float li = lv[i];
        const float ri = rv[i];
        const float rmx1 = rs_s[gb];
        const float rmx2 = rs_s[gb + 1];
        const int rdx = perm[gb];
        const float rmx = (i == rdx) ? rmx2 : rmx1;
        const float m = lrelu(li + rmx);
        const float c1 = rmx1;
        const float alpha = __expf(li + c1 - m);
        const float beta = __expf(0.2f * (li + c1) - m);
        const float diag = __expf(lrelu(li + ri) - m);

        const int k = kout[gb + i];

        const float SAk = (k > 0) ? (sAOff[bh * NCH + ((k - 1) >> 7)] + SAloc[gb + k - 1]) : 0.f;
        const float SBk = (k < N) ? (sBOff[bh * NCH + (k >> 7)] + SBloc[gb + k]) : 0.f;
        const float Z = fmaf(alpha, SAk, beta * SBk) - diag;
        const float invZ = 1.f / Z;

        float pa[8] = {}, pb[8] = {};
        if (k > 0) {
            const int kk = k - 1, ch = kk >> 7;
            const f16x8 v = *(const f16x8*)&PA[(gb + kk) * D + c0];
            const float4 o0 = *(const float4*)&AOff[(size_t)(bh * NCH + ch) * D + c0];
            const float4 o1 = *(const float4*)&AOff[(size_t)(bh * NCH + ch) * D + c0 + 4];
            pa[0] = (float)v[0] + o0.x; pa[1] = (float)v[1] + o0.y;
            pa[2] = (float)v[2] + o0.z; pa[3] = (float)v[3] + o0.w;
            pa[4] = (float)v[4] + o1.x; pa[5] = (float)v[5] + o1.y;
            pa[6] = (float)v[6] + o1.z; pa[7] = (float)v[7] + o1.w;
        }
        if (k < N) {
            const int ch = k >> 7;
            const f16x8 v = *(const f16x8*)&PB[(gb + k) * D + c0];
            const float4 o0 = *(const float4*)&BOffS[(size_t)(bh * NCH + ch) * D + c0];
            const float4 o1 = *(const float4*)&BOffS[(size_t)(bh * NCH + ch) * D + c0 + 4];
            pb[0] = (float)v[0] + o0.x; pb[1] = (float)v[1] + o0.y;
            pb[2] = (float)v[2] + o0.z; pb[3] = (float)v[3] + o0.w;
            pb[4] = (float)v[4] + o1.x; pb[5] = (float)v[5] + o1.y;
            pb[6] = (float)v[6] + o1.z; pb[7] = (float)v[7] + o1.w;
        }

        const float* hr = h + (size_t)(b * N + i) * C2 + head * D + c0;
        const float4 h0v = *(const float4*)&hr[0];
        const float4 h1v = *(const float4*)&hr[4];
        const float hv[8] = {h0v.x, h0v.y, h0v.z, h0v.w, h1v.x, h1v.y, h1v.z, h1v.w};
        float o[8];
#pragma unroll
        for (int q = 0; q < 8; ++q) {
            const float num = alpha * pa[q] + beta * pb[q] - diag * hv[q];
            float v = fmaf(num, invZ, hv[q]);
            o[q] = v > 0.f ? v : (__expf(v) - 1.f);
        }
        const size_t oidx = (size_t)(b * N + i) * C2 + head * D + c0;
        if (final_layer) {
            *(float4*)&out_f32[oidx] = make_float4(o[0], o[1], o[2], o[3]);
            *(float4*)&out_f32[oidx + 4] = make_float4(o[4], o[5], o[6], o[7]);
        } else {
            f16x8 ov;
#pragma unroll
            for (int q = 0; q < 8; ++q) ov[q] = (f16)o[q];
            *(f16x8*)&out_f16[oidx] = ov;
        }
    }
}

extern "C" void kernel_launch(void* const* d_in, const int* in_sizes, int n_in,
                              void* d_out, int out_size, void* d_ws, size_t ws_size,
                              hipStream_t stream)
{
    const float* x = (const float*)d_in[0];
    float* ws = (float*)d_ws;
    size_t off = 0;
    f16* xh = (f16*)(ws + off);   off += (size_t)M_ * C2 / 2;
    f16* WcT = (f16*)(ws + off);  off += (size_t)C2 * C2;
    float* h = ws + off;          off += (size_t)M_ * C2;
    float* l0 = ws + off;         off += (size_t)B_ * N;
    float* r0 = ws + off;         off += (size_t)B_ * N;
    float* l1 = ws + off;         off += (size_t)B_ * N;
    float* r1 = ws + off;         off += (size_t)B_ * N;
    float* rs_s = ws + off;       off += (size_t)16 * N;
    int* perm = (int*)(ws + off); off += (size_t)16 * N;
    int* kout = (int*)(ws + off); off += (size_t)16 * N;
    float* SAloc = ws + off;      off += (size_t)16 * N;
    float* SBloc = ws + off;      off += (size_t)16 * N;
    f16* PA = (f16*)(ws + off);   off += (size_t)16 * N * D / 2;
    f16* PB = (f16*)(ws + off);   off += (size_t)16 * N * D / 2;
    float* totA = ws + off;       off += (size_t)16 * NCH * D;
    float* totB = ws + off;       off += (size_t)16 * NCH * D;
    float* AOff = ws + off;       off += (size_t)16 * NCH * D;
    float* BOffS = ws + off;      off += (size_t)16 * NCH * D;
    float* stA = ws + off;        off += (size_t)16 * NCH;
    float* stB = ws + off;        off += (size_t)16 * NCH;
    float* sAOff = ws + off;      off += (size_t)16 * NCH;
    float* sBOff = ws + off;      off += (size_t)16 * NCH;

    const int REPS = 4;   // measurement round: every per-stage kernel runs its body 4x

    cvt_x_kernel<<<M_ * C2 / 1024, 256, 0, stream>>>(x, xh, REPS);
    cvt_w_kernel<<<dim3(C2, 2), C2, 0, stream>>>(
        (const float*)d_in[2], (const float*)d_in[5],
        (const float*)d_in[8], (const float*)d_in[11], WcT);

    for (int layer = 0; layer < 2; ++layer) {
        const int base = 2 + layer * 6;
        const float* b0 = (const float*)d_in[base + 1];
        const float* a0 = (const float*)d_in[base + 2];
        const float* b1 = (const float*)d_in[base + 4];
        const float* a1 = (const float*)d_in[base + 5];

        gemm_lr_kernel<<<M_ / 64, 256, 0, stream>>>(
            xh, WcT + (size_t)layer * C2 * C2, b0, b1, a0, a1, h, l0, r0, l1, r1, REPS);
        rank_kernel<<<dim3(N / 256, B_ * H), 256, 0, stream>>>(r0, r1, l0, l1, rs_s, perm, kout, REPS);
        scanA_kernel<<<dim3(NCH, B_ * H), 256, 0, stream>>>(
            h, perm, rs_s, PA, PB, SAloc, SBloc, totA, totB, stA, stB, REPS);
        scanB_kernel<<<B_ * H, 128, 0, stream>>>(totA, totB, stA, stB, AOff, BOffS, sAOff, sBOff, REPS);
        out_kernel<<<dim3(N / 16, H, B_), 256, 0, stream>>>(
            h, l0, l1, r0, r1, perm, rs_s, kout, SAloc, SBloc, sAOff, sBOff,
            PA, PB, AOff, BOffS, (float*)d_out, xh, layer == 1 ? 1 : 0, REPS);
    }
}

// Round 7
// 257.147 us; speedup vs baseline: 2.0546x; 2.0546x over previous
//
#include <hip/hip_runtime.h>
#include <math.h>

#define ALPHA_SLOPE 0.2f

typedef _Float16 f16;
typedef f16 f16x4 __attribute__((ext_vector_type(4)));
typedef f16 f16x8 __attribute__((ext_vector_type(8)));
typedef float f32x4 __attribute__((ext_vector_type(4)));

constexpr int B_ = 8, N = 2048, F = 256, D = 128, H = 2;
constexpr int C2 = H * D;           // 256
constexpr int M_ = B_ * N;          // 16384
constexpr int NCH = 16;             // scan chunks
constexpr int CHL = N / NCH;        // 128

__device__ __forceinline__ float lrelu(float x) { return fmaxf(x, ALPHA_SLOPE * x); }

// ---------- fused: x fp32->f16 (blocks 0..4095) + both W -> WcT f16 (blocks 4096..4223) ----------
__global__ __launch_bounds__(256) void cvt_kernel(
    const float* __restrict__ x, f16* __restrict__ xh,
    const float* __restrict__ W00, const float* __restrict__ W01,
    const float* __restrict__ W10, const float* __restrict__ W11,
    f16* __restrict__ WcT)
{
    const int t = threadIdx.x;
    if (blockIdx.x < 4096) {
        const int idx = (blockIdx.x * 256 + t) * 4;
        const float4 v = *(const float4*)&x[idx];
        f16x4 o; o[0] = (f16)v.x; o[1] = (f16)v.y; o[2] = (f16)v.z; o[3] = (f16)v.w;
        *(f16x4*)&xh[idx] = o;
    } else {
        const int w = blockIdx.x - 4096;           // [0,128): 4 (layer,c) pairs each
#pragma unroll
        for (int p = 0; p < 4; ++p) {
            const int pair = w * 4 + p;            // [0,512)
            const int layer = pair >> 8, c = pair & 255;
            const float* __restrict__ W0 = layer ? W10 : W00;
            const float* __restrict__ W1 = layer ? W11 : W01;
            const float v = (c < D) ? W0[t * D + c] : W1[t * D + (c - D)];
            WcT[(size_t)layer * C2 * C2 + c * C2 + t] = (f16)v;
        }
    }
}

// ---------- fused: h = xh@WcT^T + bias (MFMA), coalesced h store, l/r from LDS tile ----------
__global__ __launch_bounds__(256) void gemm_lr_kernel(
    const f16* __restrict__ xh, const f16* __restrict__ WcT,
    const float* __restrict__ b0, const float* __restrict__ b1,
    const float* __restrict__ a0, const float* __restrict__ a1,
    float* __restrict__ h,
    float* __restrict__ l0, float* __restrict__ r0,
    float* __restrict__ l1, float* __restrict__ r1)
{
    __shared__ float hts[64][C2 + 4];
    f16 (*xs)[C2 + 8] = (f16 (*)[C2 + 8])hts;

    const int t = threadIdx.x;
    const int row0 = blockIdx.x * 64;
#pragma unroll
    for (int p = 0; p < 8; ++p) {
        const int q = p * 256 + t;
        const int row = q >> 5, cc = q & 31;
        *(f16x8*)&xs[row][cc * 8] = *(const f16x8*)&xh[(size_t)(row0 + row) * C2 + cc * 8];
    }
    __syncthreads();
    const int w = t >> 6, l = t & 63;
    const int fm = l & 15, fk = (l >> 4) * 8;
    f32x4 acc[4][4] = {};
#pragma unroll
    for (int ks = 0; ks < 8; ++ks) {
        f16x8 af[4], bf[4];
#pragma unroll
        for (int rt = 0; rt < 4; ++rt)
            af[rt] = *(const f16x8*)&xs[rt * 16 + fm][ks * 32 + fk];
#pragma unroll
        for (int ct = 0; ct < 4; ++ct) {
            const int col = w * 64 + ct * 16 + fm;
            bf[ct] = *(const f16x8*)&WcT[(size_t)col * C2 + ks * 32 + fk];
        }
#pragma unroll
        for (int rt = 0; rt < 4; ++rt)
#pragma unroll
            for (int ct = 0; ct < 4; ++ct)
                acc[rt][ct] = __builtin_amdgcn_mfma_f32_16x16x32_f16(af[rt], bf[ct], acc[rt][ct], 0, 0, 0);
    }
    __syncthreads();
#pragma unroll
    for (int rt = 0; rt < 4; ++rt)
#pragma unroll
        for (int ct = 0; ct < 4; ++ct) {
            const int col = w * 64 + ct * 16 + fm;
            const float bias = (col < D) ? b0[col] : b1[col - D];
#pragma unroll
            for (int q = 0; q < 4; ++q) {
                const int row = rt * 16 + (l >> 4) * 4 + q;
                hts[row][col] = acc[rt][ct][q] + bias;
            }
        }
    __syncthreads();
#pragma unroll
    for (int p = 0; p < 16; ++p) {
        const int q = p * 256 + t;
        const int row = q >> 6, c4 = q & 63;
        *(float4*)&h[(size_t)(row0 + row) * C2 + c4 * 4] = *(const float4*)&hts[row][c4 * 4];
    }
    const int lrow = w * 16 + (l & 15);
    const int qtr = l >> 4;
    const float* __restrict__ ab = (qtr >= 2) ? a1 : a0;
    const int cb = (qtr & 1) * 64;
    float lv = 0.f, rv = 0.f;
#pragma unroll
    for (int c4 = 0; c4 < 16; ++c4) {
        const float4 hv = *(const float4*)&hts[lrow][qtr * 64 + c4 * 4];
        const float4 alv = *(const float4*)&ab[cb + c4 * 4];
        const float4 arv = *(const float4*)&ab[128 + cb + c4 * 4];
        lv += hv.x * alv.x + hv.y * alv.y + hv.z * alv.z + hv.w * alv.w;
        rv += hv.x * arv.x + hv.y * arv.y + hv.z * arv.z + hv.w * arv.w;
    }
    lv += __shfl_xor(lv, 16, 64);
    rv += __shfl_xor(rv, 16, 64);
    const int grow = row0 + lrow;
    if (qtr == 0) { l0[grow] = lv; r0[grow] = rv; }
    else if (qtr == 2) { l1[grow] = lv; r1[grow] = rv; }
}

// ---------- rank sort + k_i count, 4-way j-split: 32 blocks/bh, 64 elems/block ----------
__global__ __launch_bounds__(256) void rank_kernel(
    const float* __restrict__ r0, const float* __restrict__ r1,
    const float* __restrict__ l0, const float* __restrict__ l1,
    float* __restrict__ rs_s, int* __restrict__ perm, int* __restrict__ kout,
    int* __restrict__ chkcnt)
{
    const int bh = blockIdx.y;
    const float* __restrict__ r = ((bh & 1) ? r1 : r0) + (size_t)(bh >> 1) * N;
    const float* __restrict__ lp = ((bh & 1) ? l1 : l0) + (size_t)(bh >> 1) * N;
    __shared__ float rl[N];
    __shared__ int scnt[4][64], sk2[4][64];
    const int t = threadIdx.x;
    if (t == 0 && blockIdx.x == 0) chkcnt[bh] = 0;   // init for scanA's last-block trick
    for (int j = t; j < N; j += 256) rl[j] = r[j];
    __syncthreads();
    const int el = t & 63;                 // element within block
    const int q = t >> 6;                  // j-quarter handled by this wave
    const int e = blockIdx.x * 64 + el;    // global element
    const float re = rl[e];
    const float thr = -lp[e];
    const int qm = blockIdx.x >> 3;        // quarter containing e (block range within one quarter)
    int cnt = 0, k2 = 0;
    const int jlo = q * 512, jhi = jlo + 512;
    if (q < qm) {                          // all j < e: ties count
        for (int j = jlo; j < jhi; j += 4) {
            const float4 v = *(const float4*)&rl[j];
            cnt += (v.x >= re) + (v.y >= re) + (v.z >= re) + (v.w >= re);
            k2  += (v.x >= thr) + (v.y >= thr) + (v.z >= thr) + (v.w >= thr);
        }
    } else if (q > qm) {                   // all j > e: ties don't count
        for (int j = jlo; j < jhi; j += 4) {
            const float4 v = *(const float4*)&rl[j];
            cnt += (v.x > re) + (v.y > re) + (v.z > re) + (v.w > re);
            k2  += (v.x >= thr) + (v.y >= thr) + (v.z >= thr) + (v.w >= thr);
        }
    } else {                               // mixed quarter: exact tie-break
        for (int j = jlo; j < jhi; j += 4) {
            const float4 v = *(const float4*)&rl[j];
            cnt += (v.x > re) || (v.x == re && (j + 0) < e);
            cnt += (v.y > re) || (v.y == re && (j + 1) < e);
            cnt += (v.z > re) || (v.z == re && (j + 2) < e);
            cnt += (v.w > re) || (v.w == re && (j + 3) < e);
            k2  += (v.x >= thr) + (v.y >= thr) + (v.z >= thr) + (v.w >= thr);
        }
    }
    scnt[q][el] = cnt; sk2[q][el] = k2;
    __syncthreads();
    if (t < 64) {
        const int c = scnt[0][t] + scnt[1][t] + scnt[2][t] + scnt[3][t];
        const int kk = sk2[0][t] + sk2[1][t] + sk2[2][t] + sk2[3][t];
        const int eg = blockIdx.x * 64 + t;
        const size_t g = (size_t)bh * N;
        rs_s[g + c] = rl[eg];
        perm[g + c] = eg;
        kout[g + eg] = kk;
    }
}

// ---------- fused chunk scans + (last block per bh) chunk-offset scans ----------
__global__ __launch_bounds__(256) void scanA_kernel(
    const float* __restrict__ h, const int* __restrict__ perm,
    const float* __restrict__ rs_s,
    f16* __restrict__ PA, f16* __restrict__ PB,
    float* __restrict__ SAloc, float* __restrict__ SBloc,
    float* __restrict__ totA, float* __restrict__ totB,
    float* __restrict__ stA, float* __restrict__ stB,
    float* __restrict__ AOff, float* __restrict__ BOffS,
    float* __restrict__ sAOff, float* __restrict__ sBOff,
    int* __restrict__ chkcnt)
{
    const int chunk = blockIdx.x, bh = blockIdx.y;
    const int b = bh >> 1, head = bh & 1;
    __shared__ float hs[CHL][D];
    __shared__ int pj[CHL];
    __shared__ float wA[CHL], wB[CHL];
    __shared__ float buf[256];
    __shared__ bool amlast;
    const int t = threadIdx.x;
    const size_t g = (size_t)bh * N + chunk * CHL;
    const float c1 = rs_s[(size_t)bh * N];
    if (t < CHL) {
        pj[t] = perm[g + t];
        const float rr = rs_s[g + t];
        const float eA = __expf(rr - c1);
        const float eB = __expf(0.2f * (rr - c1));
        wA[t] = eA; wB[t] = eB;
        buf[t] = eA;
    } else {
        const float rr = rs_s[g + (127 - (t - 128))];
        buf[t] = __expf(0.2f * (rr - c1));
    }
    __syncthreads();
    const int li = t & 127;
#pragma unroll
    for (int off = 1; off < 128; off <<= 1) {
        const float v = (li >= off) ? buf[t - off] : 0.f;
        __syncthreads();
        buf[t] += v;
        __syncthreads();
    }
    if (t < 128) SAloc[g + t] = buf[t];
    else SBloc[g + (127 - li)] = buf[t];
    if (t == 127) stA[bh * NCH + chunk] = buf[127];
    if (t == 255) stB[bh * NCH + chunk] = buf[255];
#pragma unroll
    for (int p = 0; p < 16; ++p) {
        const int q = p * 256 + t;
        const int row = q >> 5, c4 = q & 31;
        const float* src = h + (size_t)(b * N + pj[row]) * C2 + head * D;
        *(float4*)&hs[row][c4 * 4] = *(const float4*)&src[c4 * 4];
    }
    __syncthreads();
    if (t < D) {
        const int d = t;
        float acc = 0.f;
        for (int j = 0; j < CHL; ++j) {
            acc = fmaf(wA[j], hs[j][d], acc);
            PA[(g + j) * D + d] = (f16)acc;
        }
        totA[(size_t)(bh * NCH + chunk) * D + d] = acc;
    } else {
        const int d = t - D;
        float acc = 0.f;
        for (int jj = 0; jj < CHL; ++jj) {
            const int j = CHL - 1 - jj;
            acc = fmaf(wB[j], hs[j][d], acc);
            PB[(g + j) * D + d] = (f16)acc;
        }
        totB[(size_t)(bh * NCH + chunk) * D + d] = acc;
    }
    // ---- last block of this bh computes chunk offsets (absorbed scanB) ----
    __threadfence();
    __syncthreads();
    if (t == 0) amlast = (atomicAdd(&chkcnt[bh], 1) == NCH - 1);
    __syncthreads();
    if (amlast) {
        __threadfence();   // acquire: other chunks' totA/totB/stA/stB now visible
        if (t < 128) {
            const int d = t;
            float accA = 0.f;
            for (int q = 0; q < NCH; ++q) {
                AOff[(size_t)(bh * NCH + q) * D + d] = accA;
                accA += totA[(size_t)(bh * NCH + q) * D + d];
            }
        } else {
            const int d = t - 128;
            float accB = 0.f;
            for (int q = NCH - 1; q >= 0; --q) {
                BOffS[(size_t)(bh * NCH + q) * D + d] = accB;
                accB += totB[(size_t)(bh * NCH + q) * D + d];
            }
        }
        if (t == 0) {
            float a = 0.f;
            for (int q = 0; q < NCH; ++q) { sAOff[bh * NCH + q] = a; a += stA[bh * NCH + q]; }
        } else if (t == 1) {
            float a = 0.f;
            for (int q = NCH - 1; q >= 0; --q) { sBOff[bh * NCH + q] = a; a += stB[bh * NCH + q]; }
        }
    }
}

// ---------- output: streaming combine + elu ----------
__global__ __launch_bounds__(256) void out_kernel(
    const float* __restrict__ h,
    const float* __restrict__ l0v, const float* __restrict__ l1v,
    const float* __restrict__ r0v, const float* __restrict__ r1v,
    const int* __restrict__ perm, const float* __restrict__ rs_s,
    const int* __restrict__ kout,
    const float* __restrict__ SAloc, const float* __restrict__ SBloc,
    const float* __restrict__ sAOff, const float* __restrict__ sBOff,
    const f16* __restrict__ PA, const f16* __restrict__ PB,
    const float* __restrict__ AOff, const float* __restrict__ BOffS,
    float* __restrict__ out_f32, f16* __restrict__ out_f16, const int final_layer)
{
    const int head = blockIdx.y, b = blockIdx.z;
    const int bh = b * H + head;
    const float* __restrict__ lv = (head ? l1v : l0v) + (size_t)b * N;
    const float* __restrict__ rv = (head ? r1v : r0v) + (size_t)b * N;
    const int t = threadIdx.x;
    const size_t gb = (size_t)bh * N;

    const int i = blockIdx.x * 16 + (t >> 4);
    const int c0 = (t & 15) * 8;
    const float li = lv[i];
    const float ri = rv[i];
    const float rmx1 = rs_s[gb];
    const float rmx2 = rs_s[gb + 1];
    const int rdx = perm[gb];
    const float rmx = (i == rdx) ? rmx2 : rmx1;
    const float m = lrelu(li + rmx);
    const float c1 = rmx1;
    const float alpha = __expf(li + c1 - m);
    const float beta = __expf(0.2f * (li + c1) - m);
    const float diag = __expf(lrelu(li + ri) - m);

    const int k = kout[gb + i];

    const float SAk = (k > 0) ? (sAOff[bh * NCH + ((k - 1) >> 7)] + SAloc[gb + k - 1]) : 0.f;
    const float SBk = (k < N) ? (sBOff[bh * NCH + (k >> 7)] + SBloc[gb + k]) : 0.f;
    const float Z = fmaf(alpha, SAk, beta * SBk) - diag;
    const float invZ = 1.f / Z;

    float pa[8] = {}, pb[8] = {};
    if (k > 0) {
        const int kk = k - 1, ch = kk >> 7;
        const f16x8 v = *(const f16x8*)&PA[(gb + kk) * D + c0];
        const float4 o0 = *(const float4*)&AOff[(size_t)(bh * NCH + ch) * D + c0];
        const float4 o1 = *(const float4*)&AOff[(size_t)(bh * NCH + ch) * D + c0 + 4];
        pa[0] = (float)v[0] + o0.x; pa[1] = (float)v[1] + o0.y;
        pa[2] = (float)v[2] + o0.z; pa[3] = (float)v[3] + o0.w;
        pa[4] = (float)v[4] + o1.x; pa[5] = (float)v[5] + o1.y;
        pa[6] = (float)v[6] + o1.z; pa[7] = (float)v[7] + o1.w;
    }
    if (k < N) {
        const int ch = k >> 7;
        const f16x8 v = *(const f16x8*)&PB[(gb + k) * D + c0];
        const float4 o0 = *(const float4*)&BOffS[(size_t)(bh * NCH + ch) * D + c0];
        const float4 o1 = *(const float4*)&BOffS[(size_t)(bh * NCH + ch) * D + c0 + 4];
        pb[0] = (float)v[0] + o0.x; pb[1] = (float)v[1] + o0.y;
        pb[2] = (float)v[2] + o0.z; pb[3] = (float)v[3] + o0.w;
        pb[4] = (float)v[4] + o1.x; pb[5] = (float)v[5] + o1.y;
        pb[6] = (float)v[6] + o1.z; pb[7] = (float)v[7] + o1.w;
    }

    const float* hr = h + (size_t)(b * N + i) * C2 + head * D + c0;
    const float4 h0v = *(const float4*)&hr[0];
    const float4 h1v = *(const float4*)&hr[4];
    const float hv[8] = {h0v.x, h0v.y, h0v.z, h0v.w, h1v.x, h1v.y, h1v.z, h1v.w};
    float o[8];
#pragma unroll
    for (int q = 0; q < 8; ++q) {
        const float num = alpha * pa[q] + beta * pb[q] - diag * hv[q];
        float v = fmaf(num, invZ, hv[q]);
        o[q] = v > 0.f ? v : (__expf(v) - 1.f);
    }
    const size_t oidx = (size_t)(b * N + i) * C2 + head * D + c0;
    if (final_layer) {
        *(float4*)&out_f32[oidx] = make_float4(o[0], o[1], o[2], o[3]);
        *(float4*)&out_f32[oidx + 4] = make_float4(o[4], o[5], o[6], o[7]);
    } else {
        f16x8 ov;
#pragma unroll
        for (int q = 0; q < 8; ++q) ov[q] = (f16)o[q];
        *(f16x8*)&out_f16[oidx] = ov;
    }
}

extern "C" void kernel_launch(void* const* d_in, const int* in_sizes, int n_in,
                              void* d_out, int out_size, void* d_ws, size_t ws_size,
                              hipStream_t stream)
{
    const float* x = (const float*)d_in[0];
    float* ws = (float*)d_ws;
    size_t off = 0;
    f16* xh = (f16*)(ws + off);   off += (size_t)M_ * C2 / 2;
    f16* WcT = (f16*)(ws + off);  off += (size_t)C2 * C2;
    float* h = ws + off;          off += (size_t)M_ * C2;
    float* l0 = ws + off;         off += (size_t)B_ * N;
    float* r0 = ws + off;         off += (size_t)B_ * N;
    float* l1 = ws + off;         off += (size_t)B_ * N;
    float* r1 = ws + off;         off += (size_t)B_ * N;
    float* rs_s = ws + off;       off += (size_t)16 * N;
    int* perm = (int*)(ws + off); off += (size_t)16 * N;
    int* kout = (int*)(ws + off); off += (size_t)16 * N;
    float* SAloc = ws + off;      off += (size_t)16 * N;
    float* SBloc = ws + off;      off += (size_t)16 * N;
    f16* PA = (f16*)(ws + off);   off += (size_t)16 * N * D / 2;
    f16* PB = (f16*)(ws + off);   off += (size_t)16 * N * D / 2;
    float* totA = ws + off;       off += (size_t)16 * NCH * D;
    float* totB = ws + off;       off += (size_t)16 * NCH * D;
    float* AOff = ws + off;       off += (size_t)16 * NCH * D;
    float* BOffS = ws + off;      off += (size_t)16 * NCH * D;
    float* stA = ws + off;        off += (size_t)16 * NCH;
    float* stB = ws + off;        off += (size_t)16 * NCH;
    float* sAOff = ws + off;      off += (size_t)16 * NCH;
    float* sBOff = ws + off;      off += (size_t)16 * NCH;
    int* chkcnt = (int*)(ws + off); off += 16;

    cvt_kernel<<<4096 + 128, 256, 0, stream>>>(
        x, xh,
        (const float*)d_in[2], (const float*)d_in[5],
        (const float*)d_in[8], (const float*)d_in[11], WcT);

    for (int layer = 0; layer < 2; ++layer) {
        const int base = 2 + layer * 6;
        const float* b0 = (const float*)d_in[base + 1];
        const float* a0 = (const float*)d_in[base + 2];
        const float* b1 = (const float*)d_in[base + 4];
        const float* a1 = (const float*)d_in[base + 5];

        gemm_lr_kernel<<<M_ / 64, 256, 0, stream>>>(
            xh, WcT + (size_t)layer * C2 * C2, b0, b1, a0, a1, h, l0, r0, l1, r1);
        rank_kernel<<<dim3(N / 64, B_ * H), 256, 0, stream>>>(
            r0, r1, l0, l1, rs_s, perm, kout, chkcnt);
        scanA_kernel<<<dim3(NCH, B_ * H), 256, 0, stream>>>(
            h, perm, rs_s, PA, PB, SAloc, SBloc, totA, totB, stA, stB,
            AOff, BOffS, sAOff, sBOff, chkcnt);
        out_kernel<<<dim3(N / 16, H, B_), 256, 0, stream>>>(
            h, l0, l1, r0, r1, perm, rs_s, kout, SAloc, SBloc, sAOff, sBOff,
            PA, PB, AOff, BOffS, (float*)d_out, xh, layer == 1 ? 1 : 0);
    }
}

// Round 9
// 240.868 us; speedup vs baseline: 2.1934x; 1.0676x over previous
//
#include <hip/hip_runtime.h>
#include <hip/hip_cooperative_groups.h>
#include <math.h>

namespace cg = cooperative_groups;

#define ALPHA_SLOPE 0.2f

typedef _Float16 f16;
typedef f16 f16x4 __attribute__((ext_vector_type(4)));
typedef f16 f16x8 __attribute__((ext_vector_type(8)));
typedef float f32x4 __attribute__((ext_vector_type(4)));

constexpr int B_ = 8, N = 2048, D = 128, H = 2;
constexpr int C2 = H * D;           // 256
constexpr int M_ = B_ * N;          // 16384
constexpr int NCH = 32;             // scan chunks
constexpr int CHL = N / NCH;        // 64
constexpr int GRID = 512;
constexpr int SMEM_BYTES = 17664;   // max over stages; 2 blocks/CU even under 64KiB accounting

__device__ __forceinline__ float lrelu(float x) { return fmaxf(x, ALPHA_SLOPE * x); }

struct MegaArgs {
    const float* x; f16* xh; f16* WcT;
    const float *W00, *W01, *W10, *W11;
    const float *b00, *b01, *b10, *b11;
    const float *a00, *a01, *a10, *a11;
    f16* h;
    float *l0, *r0, *l1, *r1;
    float* rs_s; int* perm; int* kout;
    float *SAloc, *SBloc; f16 *PA, *PB;
    float *totA, *totB, *AOff, *BOffS, *stA, *stB, *sAOff, *sBOff;
    float* out_f32;
};

// ================= stage 0: cvt (x -> f16, W -> WcT f16) =================
__device__ __forceinline__ void stage_cvt(const MegaArgs& A, int t, int blk)
{
    for (int u = blk; u < 4224; u += GRID) {
        if (u < 4096) {
            const int idx = (u * 256 + t) * 4;
            const float4 v = *(const float4*)&A.x[idx];
            f16x4 o; o[0] = (f16)v.x; o[1] = (f16)v.y; o[2] = (f16)v.z; o[3] = (f16)v.w;
            *(f16x4*)&A.xh[idx] = o;
        } else {
            const int w = u - 4096;                    // [0,128)
#pragma unroll
            for (int p = 0; p < 4; ++p) {
                const int pair = w * 4 + p;            // [0,512)
                const int layer = pair >> 8, c = pair & 255;
                const float* __restrict__ W0 = layer ? A.W10 : A.W00;
                const float* __restrict__ W1 = layer ? A.W11 : A.W01;
                const float v = (c < D) ? W0[t * D + c] : W1[t * D + (c - D)];
                A.WcT[(size_t)layer * C2 * C2 + c * C2 + t] = (f16)v;
            }
        }
    }
}

// ================= stage 1: gemm_lr (32-row tiles, 512 units) =================
__device__ __forceinline__ void stage_gemm(const MegaArgs& A, char* smem, int t, int blk, int layer)
{
    f16 (*hts)[C2 + 8] = (f16 (*)[C2 + 8])smem;   // 32 x 264 f16 = 16896 B (x tile, then h tile)
    const f16* __restrict__ Wl = A.WcT + (size_t)layer * C2 * C2;
    const float* __restrict__ b0 = layer ? A.b10 : A.b00;
    const float* __restrict__ b1 = layer ? A.b11 : A.b01;
    const float* __restrict__ a0 = layer ? A.a10 : A.a00;
    const float* __restrict__ a1 = layer ? A.a11 : A.a01;
    const int row0 = blk * 32;
#pragma unroll
    for (int p = 0; p < 4; ++p) {
        const int q = p * 256 + t;
        const int row = q >> 5, cc = q & 31;
        *(f16x8*)&hts[row][cc * 8] = *(const f16x8*)&A.xh[(size_t)(row0 + row) * C2 + cc * 8];
    }
    __syncthreads();
    const int w = t >> 6, l = t & 63;
    const int fm = l & 15, fk = (l >> 4) * 8;
    f32x4 acc[2][4] = {};
#pragma unroll
    for (int ks = 0; ks < 8; ++ks) {
        f16x8 af[2], bf[4];
#pragma unroll
        for (int rt = 0; rt < 2; ++rt)
            af[rt] = *(const f16x8*)&hts[rt * 16 + fm][ks * 32 + fk];
#pragma unroll
        for (int ct = 0; ct < 4; ++ct) {
            const int col = w * 64 + ct * 16 + fm;
            bf[ct] = *(const f16x8*)&Wl[(size_t)col * C2 + ks * 32 + fk];
        }
#pragma unroll
        for (int rt = 0; rt < 2; ++rt)
#pragma unroll
            for (int ct = 0; ct < 4; ++ct)
                acc[rt][ct] = __builtin_amdgcn_mfma_f32_16x16x32_f16(af[rt], bf[ct], acc[rt][ct], 0, 0, 0);
    }
    __syncthreads();   // x reads done; reuse as h tile (f16)
#pragma unroll
    for (int rt = 0; rt < 2; ++rt)
#pragma unroll
        for (int ct = 0; ct < 4; ++ct) {
            const int col = w * 64 + ct * 16 + fm;
            const float bias = (col < D) ? b0[col] : b1[col - D];
#pragma unroll
            for (int q = 0; q < 4; ++q) {
                const int row = rt * 16 + (l >> 4) * 4 + q;
                hts[row][col] = (f16)(acc[rt][ct][q] + bias);
            }
        }
    __syncthreads();
    // coalesced h store (f16)
#pragma unroll
    for (int p = 0; p < 4; ++p) {
        const int q = p * 256 + t;
        const int row = q >> 5, cc = q & 31;
        *(f16x8*)&A.h[(size_t)(row0 + row) * C2 + cc * 8] = *(const f16x8*)&hts[row][cc * 8];
    }
    // l/r: 8 threads per row (oct), rotated cols to dodge bank conflicts
    const int lrow = t >> 3;
    const int oct = t & 7;
    const float* __restrict__ ab = (oct >= 4) ? a1 : a0;
    float lv = 0.f, rv = 0.f;
#pragma unroll
    for (int c4 = 0; c4 < 8; ++c4) {
        const int cc = (c4 + oct) & 7;
        const int col = oct * 32 + cc * 4;
        const int cih = (oct & 3) * 32 + cc * 4;
        const f16x4 hf = *(const f16x4*)&hts[lrow][col];
        const float4 alv = *(const float4*)&ab[cih];
        const float4 arv = *(const float4*)&ab[128 + cih];
        const float h0 = (float)hf[0], h1 = (float)hf[1], h2 = (float)hf[2], h3 = (float)hf[3];
        lv += h0 * alv.x + h1 * alv.y + h2 * alv.z + h3 * alv.w;
        rv += h0 * arv.x + h1 * arv.y + h2 * arv.z + h3 * arv.w;
    }
    lv += __shfl_xor(lv, 1, 64); lv += __shfl_xor(lv, 2, 64);
    rv += __shfl_xor(rv, 1, 64); rv += __shfl_xor(rv, 2, 64);
    const int grow = row0 + lrow;
    if (oct == 0) { A.l0[grow] = lv; A.r0[grow] = rv; }
    else if (oct == 4) { A.l1[grow] = lv; A.r1[grow] = rv; }
}

// ================= stage 2: rank (512 units: 16 bh x 32 blocks x 64 elems) =================
__device__ __forceinline__ void stage_rank(const MegaArgs& A, char* smem, int t, int blkid)
{
    float* rl = (float*)smem;                       // 8192 B
    int* scnt = (int*)(smem + 8192);                // 1024 B
    int* sk2 = (int*)(smem + 9216);                 // 1024 B
    const int bh = blkid >> 5, blk = blkid & 31;
    const float* __restrict__ r = ((bh & 1) ? A.r1 : A.r0) + (size_t)(bh >> 1) * N;
    const float* __restrict__ lp = ((bh & 1) ? A.l1 : A.l0) + (size_t)(bh >> 1) * N;
    for (int j = t; j < N; j += 256) rl[j] = r[j];
    __syncthreads();
    const int el = t & 63;
    const int q = t >> 6;
    const int e = blk * 64 + el;
    const float re = rl[e];
    const float thr = -lp[e];
    const int qm = blk >> 3;
    int cnt = 0, k2 = 0;
    const int jlo = q * 512, jhi = jlo + 512;
    if (q < qm) {
        for (int j = jlo; j < jhi; j += 4) {
            const float4 v = *(const float4*)&rl[j];
            cnt += (v.x >= re) + (v.y >= re) + (v.z >= re) + (v.w >= re);
            k2  += (v.x >= thr) + (v.y >= thr) + (v.z >= thr) + (v.w >= thr);
        }
    } else if (q > qm) {
        for (int j = jlo; j < jhi; j += 4) {
            const float4 v = *(const float4*)&rl[j];
            cnt += (v.x > re) + (v.y > re) + (v.z > re) + (v.w > re);
            k2  += (v.x >= thr) + (v.y >= thr) + (v.z >= thr) + (v.w >= thr);
        }
    } else {
        for (int j = jlo; j < jhi; j += 4) {
            const float4 v = *(const float4*)&rl[j];
            cnt += (v.x > re) || (v.x == re && (j + 0) < e);
            cnt += (v.y > re) || (v.y == re && (j + 1) < e);
            cnt += (v.z > re) || (v.z == re && (j + 2) < e);
            cnt += (v.w > re) || (v.w == re && (j + 3) < e);
            k2  += (v.x >= thr) + (v.y >= thr) + (v.z >= thr) + (v.w >= thr);
        }
    }
    scnt[q * 64 + el] = cnt; sk2[q * 64 + el] = k2;
    __syncthreads();
    if (t < 64) {
        const int c = scnt[t] + scnt[64 + t] + scnt[128 + t] + scnt[192 + t];
        const int kk = sk2[t] + sk2[64 + t] + sk2[128 + t] + sk2[192 + t];
        const int eg = blk * 64 + t;
        const size_t g = (size_t)bh * N;
        A.rs_s[g + c] = rl[eg];
        A.perm[g + c] = eg;
        A.kout[g + eg] = kk;
    }
}

// ================= stage 3: scanA (512 units: 16 bh x 32 chunks) =================
__device__ __forceinline__ void stage_scanA(const MegaArgs& A, char* smem, int t, int blkid)
{
    f16 (*hs)[D] = (f16 (*)[D])smem;                // 64x128 f16 = 16384 B
    int* pj = (int*)(smem + 16384);                 // 256 B
    float* wA = (float*)(smem + 16640);             // 256 B
    float* wB = (float*)(smem + 16896);             // 256 B
    float* buf = (float*)(smem + 17152);            // 512 B -> ends 17664
    const int bh = blkid >> 5, chunk = blkid & 31;
    const int b = bh >> 1, head = bh & 1;
    const size_t g = (size_t)bh * N + chunk * CHL;
    const float c1 = A.rs_s[(size_t)bh * N];
    if (t < CHL) {
        pj[t] = A.perm[g + t];
        const float rr = A.rs_s[g + t];
        const float eA = __expf(rr - c1);
        const float eB = __expf(0.2f * (rr - c1));
        wA[t] = eA; wB[t] = eB;
        buf[t] = eA;
    } else if (t < 2 * CHL) {
        const float rr = A.rs_s[g + (CHL - 1 - (t - CHL))];
        buf[t] = __expf(0.2f * (rr - c1));           // reversed B for suffix via prefix
    }
    __syncthreads();
    const int li = t & (CHL - 1);
#pragma unroll
    for (int off = 1; off < CHL; off <<= 1) {
        const float v = (t < 2 * CHL && li >= off) ? buf[t - off] : 0.f;
        __syncthreads();
        if (t < 2 * CHL && li >= off) buf[t] += v;
        __syncthreads();
    }
    if (t < CHL) A.SAloc[g + t] = buf[t];
    else if (t < 2 * CHL) A.SBloc[g + (CHL - 1 - li)] = buf[t];
    if (t == CHL - 1) A.stA[bh * NCH + chunk] = buf[CHL - 1];
    if (t == 2 * CHL - 1) A.stB[bh * NCH + chunk] = buf[2 * CHL - 1];
    // gather h rows (permuted), f16: 64 rows x 16 f16x8 chunks = 1024
#pragma unroll
    for (int p = 0; p < 4; ++p) {
        const int q = p * 256 + t;
        const int row = q >> 4, c8 = q & 15;
        const f16* src = A.h + (size_t)(b * N + pj[row]) * C2 + head * D;
        *(f16x8*)&hs[row][c8 * 8] = *(const f16x8*)&src[c8 * 8];
    }
    __syncthreads();
    if (t < D) {
        const int d = t;
        float acc = 0.f;
        for (int j = 0; j < CHL; ++j) {
            acc = fmaf(wA[j], (float)hs[j][d], acc);
            A.PA[(g + j) * D + d] = (f16)acc;
        }
        A.totA[(size_t)(bh * NCH + chunk) * D + d] = acc;
    } else {
        const int d = t - D;
        float acc = 0.f;
        for (int jj = 0; jj < CHL; ++jj) {
            const int j = CHL - 1 - jj;
            acc = fmaf(wB[j], (float)hs[j][d], acc);
            A.PB[(g + j) * D + d] = (f16)acc;
        }
        A.totB[(size_t)(bh * NCH + chunk) * D + d] = acc;
    }
}

// ================= stage 4: scanB (16 active blocks) =================
__device__ __forceinline__ void stage_scanB(const MegaArgs& A, int t, int blkid)
{
    if (blkid >= 16) return;
    const int bh = blkid;
    if (t < 128) {
        const int d = t;
        float accA = 0.f;
        for (int q = 0; q < NCH; ++q) {
            A.AOff[(size_t)(bh * NCH + q) * D + d] = accA;
            accA += A.totA[(size_t)(bh * NCH + q) * D + d];
        }
    } else {
        const int d = t - 128;
        float accB = 0.f;
        for (int q = NCH - 1; q >= 0; --q) {
            A.BOffS[(size_t)(bh * NCH + q) * D + d] = accB;
            accB += A.totB[(size_t)(bh * NCH + q) * D + d];
        }
    }
    if (t == 0) {
        float a = 0.f;
        for (int q = 0; q < NCH; ++q) { A.sAOff[bh * NCH + q] = a; a += A.stA[bh * NCH + q]; }
    } else if (t == 1) {
        float a = 0.f;
        for (int q = NCH - 1; q >= 0; --q) { A.sBOff[bh * NCH + q] = a; a += A.stB[bh * NCH + q]; }
    }
}

// ================= stage 5: out (2048 units, grid-stride) =================
__device__ __forceinline__ void stage_out(const MegaArgs& A, int t, int blk, int layer)
{
    for (int u = blk; u < 2048; u += GRID) {
        const int bh = u >> 7, iblk = u & 127;
        const int b = bh >> 1, head = bh & 1;
        const float* __restrict__ lv = (head ? A.l1 : A.l0) + (size_t)b * N;
        const float* __restrict__ rv = (head ? A.r1 : A.r0) + (size_t)b * N;
        const size_t gb = (size_t)bh * N;
        const int i = iblk * 16 + (t >> 4);
        const int c0 = (t & 15) * 8;
        const float li = lv[i];
        const float ri = rv[i];
        const float rmx1 = A.rs_s[gb];
        const float rmx2 = A.rs_s[gb + 1];
        const int rdx = A.perm[gb];
        const float rmx = (i == rdx) ? rmx2 : rmx1;
        const float m = lrelu(li + rmx);
        const float alpha = __expf(li + rmx1 - m);
        const float beta = __expf(0.2f * (li + rmx1) - m);
        const float diag = __expf(lrelu(li + ri) - m);

        const int k = A.kout[gb + i];
        const float SAk = (k > 0) ? (A.sAOff[bh * NCH + ((k - 1) >> 6)] + A.SAloc[gb + k - 1]) : 0.f;
        const float SBk = (k < N) ? (A.sBOff[bh * NCH + (k >> 6)] + A.SBloc[gb + k]) : 0.f;
        const float Z = fmaf(alpha, SAk, beta * SBk) - diag;
        const float invZ = 1.f / Z;

        float pa[8] = {}, pb[8] = {};
        if (k > 0) {
            const int kk = k - 1, ch = kk >> 6;
            const f16x8 v = *(const f16x8*)&A.PA[(gb + kk) * D + c0];
            const float4 o0 = *(const float4*)&A.AOff[(size_t)(bh * NCH + ch) * D + c0];
            const float4 o1 = *(const float4*)&A.AOff[(size_t)(bh * NCH + ch) * D + c0 + 4];
            pa[0] = (float)v[0] + o0.x; pa[1] = (float)v[1] + o0.y;
            pa[2] = (float)v[2] + o0.z; pa[3] = (float)v[3] + o0.w;
            pa[4] = (float)v[4] + o1.x; pa[5] = (float)v[5] + o1.y;
            pa[6] = (float)v[6] + o1.z; pa[7] = (float)v[7] + o1.w;
        }
        if (k < N) {
            const int ch = k >> 6;
            const f16x8 v = *(const f16x8*)&A.PB[(gb + k) * D + c0];
            const float4 o0 = *(const float4*)&A.BOffS[(size_t)(bh * NCH + ch) * D + c0];
            const float4 o1 = *(const float4*)&A.BOffS[(size_t)(bh * NCH + ch) * D + c0 + 4];
            pb[0] = (float)v[0] + o0.x; pb[1] = (float)v[1] + o0.y;
            pb[2] = (float)v[2] + o0.z; pb[3] = (float)v[3] + o0.w;
            pb[4] = (float)v[4] + o1.x; pb[5] = (float)v[5] + o1.y;
            pb[6] = (float)v[6] + o1.z; pb[7] = (float)v[7] + o1.w;
        }

        const f16x8 hraw = *(const f16x8*)&A.h[(size_t)(b * N + i) * C2 + head * D + c0];
        float o[8];
#pragma unroll
        for (int q = 0; q < 8; ++q) {
            const float hv = (float)hraw[q];
            const float num = alpha * pa[q] + beta * pb[q] - diag * hv;
            float v = fmaf(num, invZ, hv);
            o[q] = v > 0.f ? v : (__expf(v) - 1.f);
        }
        const size_t oidx = (size_t)(b * N + i) * C2 + head * D + c0;
        if (layer == 1) {
            *(float4*)&A.out_f32[oidx] = make_float4(o[0], o[1], o[2], o[3]);
            *(float4*)&A.out_f32[oidx + 4] = make_float4(o[4], o[5], o[6], o[7]);
        } else {
            f16x8 ov;
#pragma unroll
            for (int q = 0; q < 8; ++q) ov[q] = (f16)o[q];
            *(f16x8*)&A.xh[oidx] = ov;
        }
    }
}

// stage < 0: full cooperative pipeline. stage >= 0: single stage (fallback path).
__global__ __launch_bounds__(256, 2) void mega_kernel(MegaArgs A, int stage, int layer_arg)
{
    __shared__ __align__(16) char smem[SMEM_BYTES];
    const int t = threadIdx.x;
    const int blk = blockIdx.x;
    if (stage < 0) {
        cg::grid_group grid = cg::this_grid();
        stage_cvt(A, t, blk);
        grid.sync();
        for (int layer = 0; layer < 2; ++layer) {
            stage_gemm(A, smem, t, blk, layer);
            grid.sync();
            stage_rank(A, smem, t, blk);
            grid.sync();
            stage_scanA(A, smem, t, blk);
            grid.sync();
            stage_scanB(A, t, blk);
            grid.sync();
            stage_out(A, t, blk, layer);
            if (layer == 0) grid.sync();
        }
    } else {
        switch (stage) {
            case 0: stage_cvt(A, t, blk); break;
            case 1: stage_gemm(A, smem, t, blk, layer_arg); break;
            case 2: stage_rank(A, smem, t, blk); break;
            case 3: stage_scanA(A, smem, t, blk); break;
            case 4: stage_scanB(A, t, blk); break;
            case 5: stage_out(A, t, blk, layer_arg); break;
        }
    }
}

extern "C" void kernel_launch(void* const* d_in, const int* in_sizes, int n_in,
                              void* d_out, int out_size, void* d_ws, size_t ws_size,
                              hipStream_t stream)
{
    float* ws = (float*)d_ws;
    size_t off = 0;
    f16* xh = (f16*)(ws + off);   off += (size_t)M_ * C2 / 2;
    f16* WcT = (f16*)(ws + off);  off += (size_t)C2 * C2;        // 2 layers f16
    f16* h = (f16*)(ws + off);    off += (size_t)M_ * C2 / 2;    // f16 now
    float* l0 = ws + off;         off += (size_t)B_ * N;
    float* r0 = ws + off;         off += (size_t)B_ * N;
    float* l1 = ws + off;         off += (size_t)B_ * N;
    float* r1 = ws + off;         off += (size_t)B_ * N;
    float* rs_s = ws + off;       off += (size_t)16 * N;
    int* perm = (int*)(ws + off); off += (size_t)16 * N;
    int* kout = (int*)(ws + off); off += (size_t)16 * N;
    float* SAloc = ws + off;      off += (size_t)16 * N;
    float* SBloc = ws + off;      off += (size_t)16 * N;
    f16* PA = (f16*)(ws + off);   off += (size_t)16 * N * D / 2;
    f16* PB = (f16*)(ws + off);   off += (size_t)16 * N * D / 2;
    float* totA = ws + off;       off += (size_t)16 * NCH * D;
    float* totB = ws + off;       off += (size_t)16 * NCH * D;
    float* AOff = ws + off;       off += (size_t)16 * NCH * D;
    float* BOffS = ws + off;      off += (size_t)16 * NCH * D;
    float* stA = ws + off;        off += (size_t)16 * NCH;
    float* stB = ws + off;        off += (size_t)16 * NCH;
    float* sAOff = ws + off;      off += (size_t)16 * NCH;
    float* sBOff = ws + off;      off += (size_t)16 * NCH;

    MegaArgs a;
    a.x = (const float*)d_in[0];
    a.xh = xh; a.WcT = WcT;
    a.W00 = (const float*)d_in[2];  a.b00 = (const float*)d_in[3];  a.a00 = (const float*)d_in[4];
    a.W01 = (const float*)d_in[5];  a.b01 = (const float*)d_in[6];  a.a01 = (const float*)d_in[7];
    a.W10 = (const float*)d_in[8];  a.b10 = (const float*)d_in[9];  a.a10 = (const float*)d_in[10];
    a.W11 = (const float*)d_in[11]; a.b11 = (const float*)d_in[12]; a.a11 = (const float*)d_in[13];
    a.h = h; a.l0 = l0; a.r0 = r0; a.l1 = l1; a.r1 = r1;
    a.rs_s = rs_s; a.perm = perm; a.kout = kout;
    a.SAloc = SAloc; a.SBloc = SBloc; a.PA = PA; a.PB = PB;
    a.totA = totA; a.totB = totB; a.AOff = AOff; a.BOffS = BOffS;
    a.stA = stA; a.stB = stB; a.sAOff = sAOff; a.sBOff = sBOff;
    a.out_f32 = (float*)d_out;

    // Capture-safe host-side occupancy check: mirror the runtime's cooperative
    // validation so we never enqueue a coop launch that would be rejected.
    int maxB = 0;
    (void)hipOccupancyMaxActiveBlocksPerMultiprocessor(&maxB, mega_kernel, 256, 0);

    if (maxB * 256 >= GRID) {
        int stage = -1, layer = 0;
        void* kargs[] = { &a, &stage, &layer };
        hipLaunchCooperativeKernel((const void*)mega_kernel, dim3(GRID), dim3(256),
                                   kargs, 0, stream);
    } else {
        // Fallback: same kernel, per-stage normal launches (round-7-style schedule).
        mega_kernel<<<GRID, 256, 0, stream>>>(a, 0, 0);
        for (int layer = 0; layer < 2; ++layer) {
            mega_kernel<<<GRID, 256, 0, stream>>>(a, 1, layer);
            mega_kernel<<<GRID, 256, 0, stream>>>(a, 2, layer);
            mega_kernel<<<GRID, 256, 0, stream>>>(a, 3, layer);
            mega_kernel<<<16,   256, 0, stream>>>(a, 4, layer);
            mega_kernel<<<GRID, 256, 0, stream>>>(a, 5, layer);
        }
    }
}

// Round 10
// 206.879 us; speedup vs baseline: 2.5538x; 1.1643x over previous
//
#include <hip/hip_runtime.h>
#include <math.h>

#define ALPHA_SLOPE 0.2f

typedef _Float16 f16;
typedef f16 f16x4 __attribute__((ext_vector_type(4)));
typedef f16 f16x8 __attribute__((ext_vector_type(8)));
typedef float f32x4 __attribute__((ext_vector_type(4)));

constexpr int B_ = 8, N = 2048, D = 128, H = 2;
constexpr int C2 = H * D;           // 256
constexpr int M_ = B_ * N;          // 16384
constexpr int NCH = 32;             // scan chunks
constexpr int CHL = N / NCH;        // 64

__device__ __forceinline__ float lrelu(float x) { return fmaxf(x, ALPHA_SLOPE * x); }

// ---------- fused cvt: x fp32->f16 (blocks 0..4095) + W -> WcT f16 (4096..4223) ----------
__global__ __launch_bounds__(256) void cvt_kernel(
    const float* __restrict__ x, f16* __restrict__ xh,
    const float* __restrict__ W00, const float* __restrict__ W01,
    const float* __restrict__ W10, const float* __restrict__ W11,
    f16* __restrict__ WcT)
{
    const int t = threadIdx.x;
    if (blockIdx.x < 4096) {
        const int idx = (blockIdx.x * 256 + t) * 4;
        const float4 v = *(const float4*)&x[idx];
        f16x4 o; o[0] = (f16)v.x; o[1] = (f16)v.y; o[2] = (f16)v.z; o[3] = (f16)v.w;
        *(f16x4*)&xh[idx] = o;
    } else {
        const int w = blockIdx.x - 4096;           // [0,128)
#pragma unroll
        for (int p = 0; p < 4; ++p) {
            const int pair = w * 4 + p;            // [0,512)
            const int layer = pair >> 8, c = pair & 255;
            const float* __restrict__ W0 = layer ? W10 : W00;
            const float* __restrict__ W1 = layer ? W11 : W01;
            const float v = (c < D) ? W0[t * D + c] : W1[t * D + (c - D)];
            WcT[(size_t)layer * C2 * C2 + c * C2 + t] = (f16)v;
        }
    }
}

// ---------- gemm_lr: 32-row tiles, MFMA, f16 h store, l/r from LDS tile ----------
__global__ __launch_bounds__(256) void gemm_lr_kernel(
    const f16* __restrict__ xh, const f16* __restrict__ Wl,
    const float* __restrict__ b0, const float* __restrict__ b1,
    const float* __restrict__ a0, const float* __restrict__ a1,
    f16* __restrict__ h,
    float* __restrict__ l0, float* __restrict__ r0,
    float* __restrict__ l1, float* __restrict__ r1)
{
    __shared__ f16 hts[32][C2 + 8];   // 16896 B: x tile, then h tile
    const int t = threadIdx.x;
    const int row0 = blockIdx.x * 32;
#pragma unroll
    for (int p = 0; p < 4; ++p) {
        const int q = p * 256 + t;
        const int row = q >> 5, cc = q & 31;
        *(f16x8*)&hts[row][cc * 8] = *(const f16x8*)&xh[(size_t)(row0 + row) * C2 + cc * 8];
    }
    __syncthreads();
    const int w = t >> 6, l = t & 63;
    const int fm = l & 15, fk = (l >> 4) * 8;
    f32x4 acc[2][4] = {};
#pragma unroll
    for (int ks = 0; ks < 8; ++ks) {
        f16x8 af[2], bf[4];
#pragma unroll
        for (int rt = 0; rt < 2; ++rt)
            af[rt] = *(const f16x8*)&hts[rt * 16 + fm][ks * 32 + fk];
#pragma unroll
        for (int ct = 0; ct < 4; ++ct) {
            const int col = w * 64 + ct * 16 + fm;
            bf[ct] = *(const f16x8*)&Wl[(size_t)col * C2 + ks * 32 + fk];
        }
#pragma unroll
        for (int rt = 0; rt < 2; ++rt)
#pragma unroll
            for (int ct = 0; ct < 4; ++ct)
                acc[rt][ct] = __builtin_amdgcn_mfma_f32_16x16x32_f16(af[rt], bf[ct], acc[rt][ct], 0, 0, 0);
    }
    __syncthreads();   // x reads done; reuse as h tile (f16)
#pragma unroll
    for (int rt = 0; rt < 2; ++rt)
#pragma unroll
        for (int ct = 0; ct < 4; ++ct) {
            const int col = w * 64 + ct * 16 + fm;
            const float bias = (col < D) ? b0[col] : b1[col - D];
#pragma unroll
            for (int q = 0; q < 4; ++q) {
                const int row = rt * 16 + (l >> 4) * 4 + q;
                hts[row][col] = (f16)(acc[rt][ct][q] + bias);
            }
        }
    __syncthreads();
#pragma unroll
    for (int p = 0; p < 4; ++p) {
        const int q = p * 256 + t;
        const int row = q >> 5, cc = q & 31;
        *(f16x8*)&h[(size_t)(row0 + row) * C2 + cc * 8] = *(const f16x8*)&hts[row][cc * 8];
    }
    // l/r: 8 threads per row (oct), rotated cols to dodge bank conflicts
    const int lrow = t >> 3;
    const int oct = t & 7;
    const float* __restrict__ ab = (oct >= 4) ? a1 : a0;
    float lv = 0.f, rv = 0.f;
#pragma unroll
    for (int c4 = 0; c4 < 8; ++c4) {
        const int cc = (c4 + oct) & 7;
        const int col = oct * 32 + cc * 4;
        const int cih = (oct & 3) * 32 + cc * 4;
        const f16x4 hf = *(const f16x4*)&hts[lrow][col];
        const float4 alv = *(const float4*)&ab[cih];
        const float4 arv = *(const float4*)&ab[128 + cih];
        const float h0 = (float)hf[0], h1 = (float)hf[1], h2 = (float)hf[2], h3 = (float)hf[3];
        lv += h0 * alv.x + h1 * alv.y + h2 * alv.z + h3 * alv.w;
        rv += h0 * arv.x + h1 * arv.y + h2 * arv.z + h3 * arv.w;
    }
    lv += __shfl_xor(lv, 1, 64); lv += __shfl_xor(lv, 2, 64);
    rv += __shfl_xor(rv, 1, 64); rv += __shfl_xor(rv, 2, 64);
    const int grow = row0 + lrow;
    if (oct == 0) { l0[grow] = lv; r0[grow] = rv; }
    else if (oct == 4) { l1[grow] = lv; r1[grow] = rv; }
}

// ---------- rank: 4-way j-split, 32 blocks/bh x 64 elems, + k_i count ----------
__global__ __launch_bounds__(256) void rank_kernel(
    const float* __restrict__ r0, const float* __restrict__ r1,
    const float* __restrict__ l0, const float* __restrict__ l1,
    float* __restrict__ rs_s, int* __restrict__ perm, int* __restrict__ kout)
{
    const int bh = blockIdx.y;
    const float* __restrict__ r = ((bh & 1) ? r1 : r0) + (size_t)(bh >> 1) * N;
    const float* __restrict__ lp = ((bh & 1) ? l1 : l0) + (size_t)(bh >> 1) * N;
    __shared__ float rl[N];
    __shared__ int scnt[4][64], sk2[4][64];
    const int t = threadIdx.x;
    for (int j = t; j < N; j += 256) rl[j] = r[j];
    __syncthreads();
    const int el = t & 63;
    const int q = t >> 6;
    const int e = blockIdx.x * 64 + el;
    const float re = rl[e];
    const float thr = -lp[e];
    const int qm = blockIdx.x >> 3;
    int cnt = 0, k2 = 0;
    const int jlo = q * 512, jhi = jlo + 512;
    if (q < qm) {
        for (int j = jlo; j < jhi; j += 4) {
            const float4 v = *(const float4*)&rl[j];
            cnt += (v.x >= re) + (v.y >= re) + (v.z >= re) + (v.w >= re);
            k2  += (v.x >= thr) + (v.y >= thr) + (v.z >= thr) + (v.w >= thr);
        }
    } else if (q > qm) {
        for (int j = jlo; j < jhi; j += 4) {
            const float4 v = *(const float4*)&rl[j];
            cnt += (v.x > re) + (v.y > re) + (v.z > re) + (v.w > re);
            k2  += (v.x >= thr) + (v.y >= thr) + (v.z >= thr) + (v.w >= thr);
        }
    } else {
        for (int j = jlo; j < jhi; j += 4) {
            const float4 v = *(const float4*)&rl[j];
            cnt += (v.x > re) || (v.x == re && (j + 0) < e);
            cnt += (v.y > re) || (v.y == re && (j + 1) < e);
            cnt += (v.z > re) || (v.z == re && (j + 2) < e);
            cnt += (v.w > re) || (v.w == re && (j + 3) < e);
            k2  += (v.x >= thr) + (v.y >= thr) + (v.z >= thr) + (v.w >= thr);
        }
    }
    scnt[q][el] = cnt; sk2[q][el] = k2;
    __syncthreads();
    if (t < 64) {
        const int c = scnt[0][t] + scnt[1][t] + scnt[2][t] + scnt[3][t];
        const int kk = sk2[0][t] + sk2[1][t] + sk2[2][t] + sk2[3][t];
        const int eg = blockIdx.x * 64 + t;
        const size_t g = (size_t)bh * N;
        rs_s[g + c] = rl[eg];
        perm[g + c] = eg;
        kout[g + eg] = kk;
    }
}

// ---------- scanA: per-chunk weights + local scalar scans + vector scans + totals ----------
__global__ __launch_bounds__(256) void scanA_kernel(
    const f16* __restrict__ h, const int* __restrict__ perm,
    const float* __restrict__ rs_s,
    f16* __restrict__ PA, f16* __restrict__ PB,
    float* __restrict__ SAloc, float* __restrict__ SBloc,
    float* __restrict__ totA, float* __restrict__ totB,
    float* __restrict__ stA, float* __restrict__ stB)
{
    __shared__ f16 hs[CHL][D];          // 16384 B
    __shared__ int pj[CHL];
    __shared__ float wA[CHL], wB[CHL];
    __shared__ float buf[2 * CHL];
    const int chunk = blockIdx.x, bh = blockIdx.y;
    const int b = bh >> 1, head = bh & 1;
    const int t = threadIdx.x;
    const size_t g = (size_t)bh * N + chunk * CHL;
    const float c1 = rs_s[(size_t)bh * N];
    if (t < CHL) {
        pj[t] = perm[g + t];
        const float rr = rs_s[g + t];
        const float eA = __expf(rr - c1);
        const float eB = __expf(0.2f * (rr - c1));
        wA[t] = eA; wB[t] = eB;
        buf[t] = eA;
    } else if (t < 2 * CHL) {
        const float rr = rs_s[g + (CHL - 1 - (t - CHL))];
        buf[t] = __expf(0.2f * (rr - c1));   // reversed B: suffix via prefix
    }
    __syncthreads();
    const int li = t & (CHL - 1);
#pragma unroll
    for (int off = 1; off < CHL; off <<= 1) {
        const float v = (t < 2 * CHL && li >= off) ? buf[t - off] : 0.f;
        __syncthreads();
        if (t < 2 * CHL && li >= off) buf[t] += v;
        __syncthreads();
    }
    if (t < CHL) SAloc[g + t] = buf[t];
    else if (t < 2 * CHL) SBloc[g + (CHL - 1 - li)] = buf[t];
    if (t == CHL - 1) stA[bh * NCH + chunk] = buf[CHL - 1];
    if (t == 2 * CHL - 1) stB[bh * NCH + chunk] = buf[2 * CHL - 1];
    // gather permuted h rows (f16)
#pragma unroll
    for (int p = 0; p < 4; ++p) {
        const int q = p * 256 + t;
        const int row = q >> 4, c8 = q & 15;
        const f16* src = h + (size_t)(b * N + pj[row]) * C2 + head * D;
        *(f16x8*)&hs[row][c8 * 8] = *(const f16x8*)&src[c8 * 8];
    }
    __syncthreads();
    if (t < D) {
        const int d = t;
        float acc = 0.f;
        for (int j = 0; j < CHL; ++j) {
            acc = fmaf(wA[j], (float)hs[j][d], acc);
            PA[(g + j) * D + d] = (f16)acc;
        }
        totA[(size_t)(bh * NCH + chunk) * D + d] = acc;
    } else {
        const int d = t - D;
        float acc = 0.f;
        for (int jj = 0; jj < CHL; ++jj) {
            const int j = CHL - 1 - jj;
            acc = fmaf(wB[j], (float)hs[j][d], acc);
            PB[(g + j) * D + d] = (f16)acc;
        }
        totB[(size_t)(bh * NCH + chunk) * D + d] = acc;
    }
}

// ---------- out: per-block chunk-offset scan in LDS (scanB folded) + combine + elu ----------
__global__ __launch_bounds__(256) void out_kernel(
    const f16* __restrict__ h,
    const float* __restrict__ l0v, const float* __restrict__ l1v,
    const float* __restrict__ r0v, const float* __restrict__ r1v,
    const int* __restrict__ perm, const float* __restrict__ rs_s,
    const int* __restrict__ kout,
    const float* __restrict__ SAloc, const float* __restrict__ SBloc,
    const float* __restrict__ stA, const float* __restrict__ stB,
    const float* __restrict__ totA, const float* __restrict__ totB,
    const f16* __restrict__ PA, const f16* __restrict__ PB,
    float* __restrict__ out_f32, f16* __restrict__ out_f16, const int final_layer)
{
    __shared__ float ldsA[NCH][D];      // 16384 B -> becomes exclusive prefix AOff
    __shared__ float ldsB[NCH][D];      // 16384 B -> becomes exclusive suffix BOffS
    __shared__ float lsA[NCH], lsB[NCH];
    const int head = blockIdx.y, b = blockIdx.z;
    const int bh = b * H + head;
    const float* __restrict__ lv = (head ? l1v : l0v) + (size_t)b * N;
    const float* __restrict__ rv = (head ? r1v : r0v) + (size_t)b * N;
    const int t = threadIdx.x;
    const size_t gb = (size_t)bh * N;

    // load totals
#pragma unroll
    for (int p = 0; p < 4; ++p) {
        const int idx = p * 256 + t;                 // [0,1024) float4 units
        const int ch = idx >> 5, c4 = idx & 31;
        *(float4*)&ldsA[ch][c4 * 4] = *(const float4*)&totA[(size_t)(bh * NCH + ch) * D + c4 * 4];
        *(float4*)&ldsB[ch][c4 * 4] = *(const float4*)&totB[(size_t)(bh * NCH + ch) * D + c4 * 4];
    }
    if (t < NCH) lsA[t] = stA[bh * NCH + t];
    else if (t < 2 * NCH) lsB[t - NCH] = stB[bh * NCH + (t - NCH)];
    __syncthreads();
    // in-place exclusive scans
    if (t < D) {
        const int d = t;
        float acc = 0.f;
        for (int q = 0; q < NCH; ++q) {
            const float tmp = ldsA[q][d];
            ldsA[q][d] = acc;
            acc += tmp;
        }
    } else {
        const int d = t - D;
        float acc = 0.f;
        for (int q = NCH - 1; q >= 0; --q) {
            const float tmp = ldsB[q][d];
            ldsB[q][d] = acc;
            acc += tmp;
        }
    }
    if (t == 0) {
        float a = 0.f;
        for (int q = 0; q < NCH; ++q) { const float tmp = lsA[q]; lsA[q] = a; a += tmp; }
    } else if (t == 1) {
        float a = 0.f;
        for (int q = NCH - 1; q >= 0; --q) { const float tmp = lsB[q]; lsB[q] = a; a += tmp; }
    }
    __syncthreads();

    const int i = blockIdx.x * 16 + (t >> 4);
    const int c0 = (t & 15) * 8;
    const float li = lv[i];
    const float ri = rv[i];
    const float rmx1 = rs_s[gb];
    const float rmx2 = rs_s[gb + 1];
    const int rdx = perm[gb];
    const float rmx = (i == rdx) ? rmx2 : rmx1;
    const float m = lrelu(li + rmx);
    const float alpha = __expf(li + rmx1 - m);
    const float beta = __expf(0.2f * (li + rmx1) - m);
    const float diag = __expf(lrelu(li + ri) - m);

    const int k = kout[gb + i];
    const float SAk = (k > 0) ? (lsA[(k - 1) >> 6] + SAloc[gb + k - 1]) : 0.f;
    const float SBk = (k < N) ? (lsB[k >> 6] + SBloc[gb + k]) : 0.f;
    const float Z = fmaf(alpha, SAk, beta * SBk) - diag;
    const float invZ = 1.f / Z;

    float pa[8] = {}, pb[8] = {};
    if (k > 0) {
        const int kk = k - 1, ch = kk >> 6;
        const f16x8 v = *(const f16x8*)&PA[(gb + kk) * D + c0];
#pragma unroll
        for (int q = 0; q < 8; ++q) pa[q] = (float)v[q] + ldsA[ch][c0 + q];
    }
    if (k < N) {
        const int ch = k >> 6;
        const f16x8 v = *(const f16x8*)&PB[(gb + k) * D + c0];
#pragma unroll
        for (int q = 0; q < 8; ++q) pb[q] = (float)v[q] + ldsB[ch][c0 + q];
    }

    const f16x8 hraw = *(const f16x8*)&h[(size_t)(b * N + i) * C2 + head * D + c0];
    float o[8];
#pragma unroll
    for (int q = 0; q < 8; ++q) {
        const float hv = (float)hraw[q];
        const float num = alpha * pa[q] + beta * pb[q] - diag * hv;
        float v = fmaf(num, invZ, hv);
        o[q] = v > 0.f ? v : (__expf(v) - 1.f);
    }
    const size_t oidx = (size_t)(b * N + i) * C2 + head * D + c0;
    if (final_layer) {
        *(float4*)&out_f32[oidx] = make_float4(o[0], o[1], o[2], o[3]);
        *(float4*)&out_f32[oidx + 4] = make_float4(o[4], o[5], o[6], o[7]);
    } else {
        f16x8 ov;
#pragma unroll
        for (int q = 0; q < 8; ++q) ov[q] = (f16)o[q];
        *(f16x8*)&out_f16[oidx] = ov;
    }
}

extern "C" void kernel_launch(void* const* d_in, const int* in_sizes, int n_in,
                              void* d_out, int out_size, void* d_ws, size_t ws_size,
                              hipStream_t stream)
{
    float* ws = (float*)d_ws;
    size_t off = 0;
    f16* xh = (f16*)(ws + off);   off += (size_t)M_ * C2 / 2;
    f16* WcT = (f16*)(ws + off);  off += (size_t)C2 * C2;        // 2 layers f16
    f16* h = (f16*)(ws + off);    off += (size_t)M_ * C2 / 2;
    float* l0 = ws + off;         off += (size_t)B_ * N;
    float* r0 = ws + off;         off += (size_t)B_ * N;
    float* l1 = ws + off;         off += (size_t)B_ * N;
    float* r1 = ws + off;         off += (size_t)B_ * N;
    float* rs_s = ws + off;       off += (size_t)16 * N;
    int* perm = (int*)(ws + off); off += (size_t)16 * N;
    int* kout = (int*)(ws + off); off += (size_t)16 * N;
    float* SAloc = ws + off;      off += (size_t)16 * N;
    float* SBloc = ws + off;      off += (size_t)16 * N;
    f16* PA = (f16*)(ws + off);   off += (size_t)16 * N * D / 2;
    f16* PB = (f16*)(ws + off);   off += (size_t)16 * N * D / 2;
    float* totA = ws + off;       off += (size_t)16 * NCH * D;
    float* totB = ws + off;       off += (size_t)16 * NCH * D;
    float* stA = ws + off;        off += (size_t)16 * NCH;
    float* stB = ws + off;        off += (size_t)16 * NCH;

    cvt_kernel<<<4096 + 128, 256, 0, stream>>>(
        (const float*)d_in[0], xh,
        (const float*)d_in[2], (const float*)d_in[5],
        (const float*)d_in[8], (const float*)d_in[11], WcT);

    for (int layer = 0; layer < 2; ++layer) {
        const int base = 2 + layer * 6;
        const float* b0 = (const float*)d_in[base + 1];
        const float* a0 = (const float*)d_in[base + 2];
        const float* b1 = (const float*)d_in[base + 4];
        const float* a1 = (const float*)d_in[base + 5];

        gemm_lr_kernel<<<M_ / 32, 256, 0, stream>>>(
            xh, WcT + (size_t)layer * C2 * C2, b0, b1, a0, a1, h, l0, r0, l1, r1);
        rank_kernel<<<dim3(N / 64, B_ * H), 256, 0, stream>>>(
            r0, r1, l0, l1, rs_s, perm, kout);
        scanA_kernel<<<dim3(NCH, B_ * H), 256, 0, stream>>>(
            h, perm, rs_s, PA, PB, SAloc, SBloc, totA, totB, stA, stB);
        out_kernel<<<dim3(N / 16, H, B_), 256, 0, stream>>>(
            h, l0, l1, r0, r1, perm, rs_s, kout, SAloc, SBloc, stA, stB,
            totA, totB, PA, PB, (float*)d_out, xh, layer == 1 ? 1 : 0);
    }
}